// Round 1
// baseline (409.383 us; speedup 1.0000x reference)
//
#include <hip/hip_runtime.h>
#include <hip/hip_bf16.h>
#include <hip/hip_fp16.h>

#define NB 8
#define NN 256
#define KK 128
#define HH 32
#define DD 768

typedef _Float16 f16x8 __attribute__((ext_vector_type(8)));
typedef float f32x4 __attribute__((ext_vector_type(4)));

#if __has_builtin(__builtin_amdgcn_exp2f)
  #define EXP2(x) __builtin_amdgcn_exp2f(x)
#else
  #define EXP2(x) exp2f(x)
#endif

// One block per (b,i). 256 threads = 4 waves; wave w owns j in [w*64, w*64+64).
__global__ __launch_bounds__(256, 2) void gbf_main_kernel(
    const float* __restrict__ pos, const float* __restrict__ means,
    const float* __restrict__ stds, const float* __restrict__ mul_w,
    const float* __restrict__ bias_w, const float* __restrict__ l1_w,
    const float* __restrict__ l1_b, const float* __restrict__ l2_w,
    const float* __restrict__ l2_b, const int* __restrict__ x,
    const int* __restrict__ nte, float* __restrict__ attn_out,
    float* __restrict__ s_out)
{
  // all f16 tiles stored [row][col] with col_half_index ^= (row&7)<<3  (16B XOR swizzle)
  __shared__ _Float16 w1s[KK * KK];      // l1_w [h][k]      32 KB
  __shared__ _Float16 w2s[HH * KK];      // l2_w [n][k]       8 KB
  __shared__ _Float16 hs[4][16 * KK];    // per-wave h slab  16 KB
  __shared__ float xvs[NN];
  __shared__ float kms[KK], kc2s[KK], kins[KK];
  __shared__ float l1bs[KK], l2bs[HH];
  __shared__ float ssum2[4][KK];
  __shared__ unsigned char vms[NN];

  const int bx = blockIdx.x;
  const int b = bx >> 8, i = bx & 255;
  const int tid = threadIdx.x;
  const int lane = tid & 63, w = tid >> 6;
  const int g = lane >> 4, lr = lane & 15;

  const bool valid_i = (x[b * NN + i] != 0);

  // ---- setup: per-k constants ----
  if (tid < KK) {
    float sd = fabsf(stds[tid]) + 1e-5f;
    float inv = 1.0f / sd;
    kms[tid] = means[tid];
    kc2s[tid] = -0.72134752044448170f * inv * inv;   // -0.5*log2(e)/std^2
    kins[tid] = inv / sqrtf(2.0f * 3.14159f);        // 1/(SQRT_2PI*std), ref constant
    l1bs[tid] = l1_b[tid];
    if (tid < HH) l2bs[tid] = l2_b[tid];
  }
  // ---- setup: per-j xv, valid ----
  {
    const int j = tid;
    const float pix = pos[(b * NN + i) * 3 + 0];
    const float piy = pos[(b * NN + i) * 3 + 1];
    const float piz = pos[(b * NN + i) * 3 + 2];
    const float dx = pos[(b * NN + j) * 3 + 0] - pix;
    const float dy = pos[(b * NN + j) * 3 + 1] - piy;
    const float dz = pos[(b * NN + j) * 3 + 2] - piz;
    const float sq = dx * dx + dy * dy + dz * dz;
    const float dist = (sq < 1e-4f) ? 100.0f : sqrtf(sq);
    const int base = ((b * NN + i) * NN + j) * 2;
    const int e0 = nte[base], e1 = nte[base + 1];
    const float mul = 0.5f * (mul_w[e0] + mul_w[e1]);
    const float bia = 0.5f * (bias_w[e0] + bias_w[e1]);
    xvs[j] = mul * dist + bia;
    vms[j] = (x[b * NN + j] != 0) ? 1 : 0;
  }
  // ---- stage W1, W2 to LDS (f16, swizzled) ----
  for (int idx = tid; idx < KK * KK; idx += 256) {
    const int h = idx >> 7, k = idx & 127;
    w1s[(h << 7) | (k ^ ((h & 7) << 3))] = (_Float16)l1_w[idx];
  }
  for (int idx = tid; idx < HH * KK; idx += 256) {
    const int n = idx >> 7, k = idx & 127;
    w2s[(n << 7) | (k ^ ((n & 7) << 3))] = (_Float16)l2_w[idx];
  }
  __syncthreads();

  float sp[32];  // dist_emb partials; z=ks*8+ii -> k = ks*32 + g*8 + ii
#pragma unroll
  for (int z = 0; z < 32; ++z) sp[z] = 0.0f;

  _Float16* hw = &hs[w][0];

  for (int t = 0; t < 4; ++t) {
    const int jt = w * 4 + t;
    const int jg = jt * 16 + lr;
    const float xvj = xvs[jg];
    const float efm = (valid_i && vms[jg]) ? 0.0f : 1.0f;

    // ---- gbf directly into A-fragments (lane: row j = jg, k = ks*32+g*8+ii) ----
    f16x8 afrag[4];
#pragma unroll
    for (int ks = 0; ks < 4; ++ks) {
#pragma unroll
      for (int ii = 0; ii < 8; ++ii) {
        const int k = ks * 32 + g * 8 + ii;
        const float d0 = xvj - kms[k];
        const float e = EXP2(kc2s[k] * d0 * d0) * kins[k];
        sp[ks * 8 + ii] += efm * e;
        afrag[ks][ii] = (_Float16)e;
      }
    }

    // ---- GEMM1: h = gelu(gbf @ W1^T + b1), write f16 slab ----
#pragma unroll
    for (int ht = 0; ht < 8; ++ht) {
      f32x4 acc = {0.f, 0.f, 0.f, 0.f};
#pragma unroll
      for (int ks = 0; ks < 4; ++ks) {
        const int row = ht * 16 + lr;
        const int kh = (ks * 32 + g * 8) ^ ((row & 7) << 3);
        const f16x8 bf = *(const f16x8*)&w1s[(row << 7) + kh];
        acc = __builtin_amdgcn_mfma_f32_16x16x32_f16(afrag[ks], bf, acc, 0, 0, 0);
      }
      const int hcol = ht * 16 + lr;
      const float bb = l1bs[hcol];
#pragma unroll
      for (int q = 0; q < 4; ++q) {
        const float xh = acc[q] + bb;
        const float gl = 0.5f * xh * (1.0f + erff(xh * 0.70710678118f));  // exact gelu
        const int jr = g * 4 + q;
        hw[(jr << 7) + (hcol ^ ((jr & 7) << 3))] = (_Float16)gl;
      }
    }

    // ---- GEMM2 (swapped: mfma(W2, h) -> D[row=h_out][col=j]) + masked store ----
    const float maskz = (valid_i && vms[jg]) ? 0.0f : 1.0f;
#pragma unroll
    for (int nt = 0; nt < 2; ++nt) {
      f32x4 acc = {0.f, 0.f, 0.f, 0.f};
#pragma unroll
      for (int ks = 0; ks < 4; ++ks) {
        const int wrow = nt * 16 + lr;
        const f16x8 wf = *(const f16x8*)&w2s[(wrow << 7) + ((ks * 32 + g * 8) ^ ((wrow & 7) << 3))];
        const f16x8 hf = *(const f16x8*)&hw[(lr << 7) + ((ks * 32 + g * 8) ^ ((lr & 7) << 3))];
        acc = __builtin_amdgcn_mfma_f32_16x16x32_f16(wf, hf, acc, 0, 0, 0);
      }
#pragma unroll
      for (int q = 0; q < 4; ++q) {
        const int hout = nt * 16 + g * 4 + q;
        const float v = (acc[q] + l2bs[hout]) * maskz;
        attn_out[(b * HH + hout) * (NN * NN) + i * NN + jg] = v;  // coalesced over lr
      }
    }
  }

  // ---- dist_emb partial reduction (deterministic, no atomics) ----
#pragma unroll
  for (int z = 0; z < 32; ++z) {
    float v = sp[z];
    v += __shfl_xor(v, 1);
    v += __shfl_xor(v, 2);
    v += __shfl_xor(v, 4);
    v += __shfl_xor(v, 8);
    if (lr == 0) ssum2[w][(z >> 3) * 32 + g * 8 + (z & 7)] = v;
  }
  __syncthreads();
  if (tid < KK) {
    s_out[(bx << 7) + tid] =
        ssum2[0][tid] + ssum2[1][tid] + ssum2[2][tid] + ssum2[3][tid];
  }
}

// dist_emb = (S @ ep_w^T + ep_b) / 100 ; S is (2048 x 128) fp32
__global__ __launch_bounds__(256) void emb_kernel(
    const float* __restrict__ s_in, const float* __restrict__ ep_w,
    const float* __restrict__ ep_b, float* __restrict__ out)
{
  __shared__ float st[8][KK];
  const int tid = threadIdx.x;
  const int r0 = blockIdx.x * 8;
  for (int idx = tid; idx < 8 * KK; idx += 256)
    st[idx >> 7][idx & 127] = s_in[(r0 << 7) + idx];
  __syncthreads();
#pragma unroll 1
  for (int dd = 0; dd < 3; ++dd) {
    const int d = dd * 256 + tid;
    float acc[8];
#pragma unroll
    for (int r = 0; r < 8; ++r) acc[r] = 0.f;
    const float4* wrow = (const float4*)&ep_w[d << 7];
    for (int k4 = 0; k4 < 32; ++k4) {
      const float4 wv = wrow[k4];
#pragma unroll
      for (int r = 0; r < 8; ++r) {
        acc[r] += st[r][k4 * 4 + 0] * wv.x + st[r][k4 * 4 + 1] * wv.y +
                  st[r][k4 * 4 + 2] * wv.z + st[r][k4 * 4 + 3] * wv.w;
      }
    }
    const float bb = ep_b[d];
#pragma unroll
    for (int r = 0; r < 8; ++r)
      out[(r0 + r) * DD + d] = (acc[r] + bb) * 0.01f;
  }
}

extern "C" void kernel_launch(void* const* d_in, const int* in_sizes, int n_in,
                              void* d_out, int out_size, void* d_ws, size_t ws_size,
                              hipStream_t stream) {
  const float* pos    = (const float*)d_in[0];
  const float* means  = (const float*)d_in[1];
  const float* stds   = (const float*)d_in[2];
  const float* mul_w  = (const float*)d_in[3];
  const float* bias_w = (const float*)d_in[4];
  const float* l1_w   = (const float*)d_in[5];
  const float* l1_b   = (const float*)d_in[6];
  const float* l2_w   = (const float*)d_in[7];
  const float* l2_b   = (const float*)d_in[8];
  const float* ep_w   = (const float*)d_in[9];
  const float* ep_b   = (const float*)d_in[10];
  const int*   x      = (const int*)d_in[11];
  const int*   nte    = (const int*)d_in[12];

  float* out      = (float*)d_out;
  float* dist_emb = out;                 // (8,256,768)
  float* attn     = out + NB * NN * DD;  // (8,32,256,256)
  float* s_ws     = (float*)d_ws;        // 2048*128 f32 = 1 MB

  hipLaunchKernelGGL(gbf_main_kernel, dim3(NB * NN), dim3(256), 0, stream,
                     pos, means, stds, mul_w, bias_w, l1_w, l1_b, l2_w, l2_b,
                     x, nte, attn, s_ws);
  hipLaunchKernelGGL(emb_kernel, dim3(NB * NN / 8), dim3(256), 0, stream,
                     s_ws, ep_w, ep_b, dist_emb);
}

// Round 2
// 313.592 us; speedup vs baseline: 1.3055x; 1.3055x over previous
//
#include <hip/hip_runtime.h>
#include <hip/hip_bf16.h>
#include <hip/hip_fp16.h>

#define NB 8
#define NN 256
#define KK 128
#define HH 32
#define DD 768

typedef _Float16 f16x8 __attribute__((ext_vector_type(8)));
typedef float f32x4 __attribute__((ext_vector_type(4)));

#if __has_builtin(__builtin_amdgcn_exp2f)
  #define EXP2(x) __builtin_amdgcn_exp2f(x)
#else
  #define EXP2(x) exp2f(x)
#endif

// Pre-convert W1 (128x128) and W2 (32x128) f32 -> f16 in MFMA B-fragment layout:
// frag(rblk, ks): lane l holds W[rblk*16 + (l&15)][ks*32 + (l>>4)*8 + ii], ii=0..7
__global__ void prep_kernel(const float* __restrict__ l1_w,
                            const float* __restrict__ l2_w,
                            _Float16* __restrict__ w1g,
                            _Float16* __restrict__ w2g) {
  const int gid = blockIdx.x * 256 + threadIdx.x;
  if (gid < KK * KK) {
    const int r = gid >> 7, k = gid & 127;
    const int lane = (((k >> 3) & 3) << 4) | (r & 15);
    const int frag = ((r >> 4) << 2) | (k >> 5);
    w1g[((frag << 6) + lane) * 8 + (k & 7)] = (_Float16)l1_w[gid];
  } else if (gid < KK * KK + HH * KK) {
    const int g2 = gid - KK * KK;
    const int r = g2 >> 7, k = g2 & 127;
    const int lane = (((k >> 3) & 3) << 4) | (r & 15);
    const int frag = ((r >> 4) << 2) | (k >> 5);
    w2g[((frag << 6) + lane) * 8 + (k & 7)] = (_Float16)l2_w[g2];
  }
}

// One block per (b,i). 256 threads = 4 waves; per t, block covers j in [t*64,(t+1)*64),
// wave w owns j = t*64 + w*16 + lr.
__global__ __launch_bounds__(256, 4) void gbf_main_kernel(
    const float* __restrict__ pos, const float* __restrict__ means,
    const float* __restrict__ stds, const float* __restrict__ mul_w,
    const float* __restrict__ bias_w, const float* __restrict__ l1_b,
    const float* __restrict__ l2_b, const int* __restrict__ x,
    const int* __restrict__ nte, const _Float16* __restrict__ w1g,
    const _Float16* __restrict__ w2g, float* __restrict__ attn_out,
    float* __restrict__ s_out)
{
  __shared__ _Float16 hs[4][16 * KK];          // per-wave h slab, 16 KB (row-XOR-swizzled)
  __shared__ __align__(16) float att[HH][68];  // per-t attn tile, 8.5 KB
  __shared__ float xvs[NN];
  __shared__ float kms[KK], kc2s[KK], kins[KK];
  __shared__ float l1bs[KK], l2bs[HH];
  __shared__ float ssum2[4][KK];
  __shared__ unsigned char vms[NN];

  const int bx = blockIdx.x;
  const int b = bx >> 8, i = bx & 255;
  const int tid = threadIdx.x;
  const int lane = tid & 63, w = tid >> 6;
  const int g = lane >> 4, lr = lane & 15;

  const bool valid_i = (x[b * NN + i] != 0);

  // ---- setup: per-k constants ----
  if (tid < KK) {
    float sd = fabsf(stds[tid]) + 1e-5f;
    float inv = 1.0f / sd;
    kms[tid] = means[tid];
    kc2s[tid] = -0.72134752044448170f * inv * inv;   // -0.5*log2(e)/std^2
    kins[tid] = inv / sqrtf(2.0f * 3.14159f);        // 1/(SQRT_2PI*std), ref constant
    l1bs[tid] = l1_b[tid];
    if (tid < HH) l2bs[tid] = l2_b[tid];
  }
  // ---- setup: per-j xv, valid ----
  {
    const int j = tid;
    const float pix = pos[(b * NN + i) * 3 + 0];
    const float piy = pos[(b * NN + i) * 3 + 1];
    const float piz = pos[(b * NN + i) * 3 + 2];
    const float dx = pos[(b * NN + j) * 3 + 0] - pix;
    const float dy = pos[(b * NN + j) * 3 + 1] - piy;
    const float dz = pos[(b * NN + j) * 3 + 2] - piz;
    const float sq = dx * dx + dy * dy + dz * dz;
    const float dist = (sq < 1e-4f) ? 100.0f : sqrtf(sq);
    const int base = ((b * NN + i) * NN + j) * 2;
    const int e0 = nte[base], e1 = nte[base + 1];
    const float mul = 0.5f * (mul_w[e0] + mul_w[e1]);
    const float bia = 0.5f * (bias_w[e0] + bias_w[e1]);
    xvs[j] = mul * dist + bia;
    vms[j] = (x[b * NN + j] != 0) ? 1 : 0;
  }
  __syncthreads();

  float sp[32];  // dist_emb partials; z=ks*8+ii -> k = ks*32 + g*8 + ii
#pragma unroll
  for (int z = 0; z < 32; ++z) sp[z] = 0.0f;

  _Float16* hw = &hs[w][0];

  for (int t = 0; t < 4; ++t) {
    const int jg = t * 64 + w * 16 + lr;
    const float xvj = xvs[jg];
    const float efm = (valid_i && vms[jg]) ? 0.0f : 1.0f;

    // ---- gbf directly into A-fragments (lane: row j = jg, k = ks*32+g*8+ii) ----
    f16x8 afrag[4];
#pragma unroll
    for (int ks = 0; ks < 4; ++ks) {
#pragma unroll
      for (int ii = 0; ii < 8; ++ii) {
        const int k = ks * 32 + g * 8 + ii;
        const float d0 = xvj - kms[k];
        const float e = EXP2(kc2s[k] * d0 * d0) * kins[k];
        sp[ks * 8 + ii] += efm * e;
        afrag[ks][ii] = (_Float16)e;
      }
    }

    // ---- GEMM1: h = gelu(gbf @ W1^T + b1), write f16 slab ----
#pragma unroll
    for (int ht = 0; ht < 8; ++ht) {
      f32x4 acc = {0.f, 0.f, 0.f, 0.f};
#pragma unroll
      for (int ks = 0; ks < 4; ++ks) {
        const f16x8 bf = *(const f16x8*)&w1g[(((ht << 2) + ks) * 64 + lane) * 8];
        acc = __builtin_amdgcn_mfma_f32_16x16x32_f16(afrag[ks], bf, acc, 0, 0, 0);
      }
      const int hcol = ht * 16 + lr;
      const float bb = l1bs[hcol];
#pragma unroll
      for (int q = 0; q < 4; ++q) {
        const float xh = acc[q] + bb;
        const float gl = 0.5f * xh * (1.0f + erff(xh * 0.70710678118f));  // exact gelu
        const int jr = g * 4 + q;
        hw[(jr << 7) + (hcol ^ ((jr & 7) << 3))] = (_Float16)gl;
      }
    }

    // ---- GEMM2 (swapped: mfma(W2, h) -> D[row=h_out][col=j-local]) -> LDS tile ----
    const float maskz = (valid_i && vms[jg]) ? 0.0f : 1.0f;
#pragma unroll
    for (int nt = 0; nt < 2; ++nt) {
      f32x4 acc = {0.f, 0.f, 0.f, 0.f};
#pragma unroll
      for (int ks = 0; ks < 4; ++ks) {
        const f16x8 wf = *(const f16x8*)&w2g[(((nt << 2) + ks) * 64 + lane) * 8];
        const f16x8 hf = *(const f16x8*)&hw[(lr << 7) + ((ks * 32 + g * 8) ^ ((lr & 7) << 3))];
        acc = __builtin_amdgcn_mfma_f32_16x16x32_f16(wf, hf, acc, 0, 0, 0);
      }
#pragma unroll
      for (int q = 0; q < 4; ++q) {
        const int hout = nt * 16 + g * 4 + q;
        att[hout][w * 16 + lr] = (acc[q] + l2bs[hout]) * maskz;
      }
    }
    __syncthreads();

    // ---- flush attn tile: full-line nontemporal stores (256B contiguous / plane) ----
#pragma unroll
    for (int rp = 0; rp < 2; ++rp) {
      const int plane = rp * 16 + (tid >> 4);
      const int jj = (tid & 15) * 4;
      const f32x4 v = *(const f32x4*)&att[plane][jj];
      __builtin_nontemporal_store(
          v, (f32x4*)&attn_out[(b * HH + plane) * (NN * NN) + i * NN + t * 64 + jj]);
    }
    __syncthreads();
  }

  // ---- dist_emb partial reduction (deterministic, no atomics) ----
#pragma unroll
  for (int z = 0; z < 32; ++z) {
    float v = sp[z];
    v += __shfl_xor(v, 1);
    v += __shfl_xor(v, 2);
    v += __shfl_xor(v, 4);
    v += __shfl_xor(v, 8);
    if (lr == 0) ssum2[w][(z >> 3) * 32 + g * 8 + (z & 7)] = v;
  }
  __syncthreads();
  if (tid < KK) {
    s_out[(bx << 7) + tid] =
        ssum2[0][tid] + ssum2[1][tid] + ssum2[2][tid] + ssum2[3][tid];
  }
}

// dist_emb = (S @ ep_w^T + ep_b) / 100 ; S is (2048 x 128) fp32
__global__ __launch_bounds__(256) void emb_kernel(
    const float* __restrict__ s_in, const float* __restrict__ ep_w,
    const float* __restrict__ ep_b, float* __restrict__ out)
{
  __shared__ float st[8][KK];
  const int tid = threadIdx.x;
  const int r0 = blockIdx.x * 8;
  for (int idx = tid; idx < 8 * KK; idx += 256)
    st[idx >> 7][idx & 127] = s_in[(r0 << 7) + idx];
  __syncthreads();
#pragma unroll 1
  for (int dd = 0; dd < 3; ++dd) {
    const int d = dd * 256 + tid;
    float acc[8];
#pragma unroll
    for (int r = 0; r < 8; ++r) acc[r] = 0.f;
    const float4* wrow = (const float4*)&ep_w[d << 7];
    for (int k4 = 0; k4 < 32; ++k4) {
      const float4 wv = wrow[k4];
#pragma unroll
      for (int r = 0; r < 8; ++r) {
        acc[r] += st[r][k4 * 4 + 0] * wv.x + st[r][k4 * 4 + 1] * wv.y +
                  st[r][k4 * 4 + 2] * wv.z + st[r][k4 * 4 + 3] * wv.w;
      }
    }
    const float bb = ep_b[d];
#pragma unroll
    for (int r = 0; r < 8; ++r)
      out[(r0 + r) * DD + d] = (acc[r] + bb) * 0.01f;
  }
}

extern "C" void kernel_launch(void* const* d_in, const int* in_sizes, int n_in,
                              void* d_out, int out_size, void* d_ws, size_t ws_size,
                              hipStream_t stream) {
  const float* pos    = (const float*)d_in[0];
  const float* means  = (const float*)d_in[1];
  const float* stds   = (const float*)d_in[2];
  const float* mul_w  = (const float*)d_in[3];
  const float* bias_w = (const float*)d_in[4];
  const float* l1_w   = (const float*)d_in[5];
  const float* l1_b   = (const float*)d_in[6];
  const float* l2_w   = (const float*)d_in[7];
  const float* l2_b   = (const float*)d_in[8];
  const float* ep_w   = (const float*)d_in[9];
  const float* ep_b   = (const float*)d_in[10];
  const int*   x      = (const int*)d_in[11];
  const int*   nte    = (const int*)d_in[12];

  float* out      = (float*)d_out;
  float* dist_emb = out;                 // (8,256,768)
  float* attn     = out + NB * NN * DD;  // (8,32,256,256)

  _Float16* w1g = (_Float16*)d_ws;                        // 32 KB
  _Float16* w2g = (_Float16*)((char*)d_ws + 32768);       // 8 KB
  float*    s_ws = (float*)((char*)d_ws + 49152);         // 1 MB

  hipLaunchKernelGGL(prep_kernel, dim3(80), dim3(256), 0, stream,
                     l1_w, l2_w, w1g, w2g);
  hipLaunchKernelGGL(gbf_main_kernel, dim3(NB * NN), dim3(256), 0, stream,
                     pos, means, stds, mul_w, bias_w, l1_b, l2_b,
                     x, nte, w1g, w2g, attn, s_ws);
  hipLaunchKernelGGL(emb_kernel, dim3(NB * NN / 8), dim3(256), 0, stream,
                     s_ws, ep_w, ep_b, dist_emb);
}

// Round 3
// 130.105 us; speedup vs baseline: 3.1466x; 2.4103x over previous
//
#include <hip/hip_runtime.h>
#include <hip/hip_bf16.h>
#include <hip/hip_fp16.h>

#define NB 8
#define NN 256
#define KK 128
#define HH 32
#define DD 768

typedef _Float16 f16x8 __attribute__((ext_vector_type(8)));
typedef float f32x4 __attribute__((ext_vector_type(4)));

#if __has_builtin(__builtin_amdgcn_exp2f)
  #define EXP2(x) __builtin_amdgcn_exp2f(x)
#else
  #define EXP2(x) exp2f(x)
#endif

// f32 -> f16 row-major copies of l1_w (128x128) and l2_w (32x128)
__global__ void prep_kernel(const float* __restrict__ l1_w,
                            const float* __restrict__ l2_w,
                            _Float16* __restrict__ w1h,
                            _Float16* __restrict__ w2h) {
  const int gid = blockIdx.x * 256 + threadIdx.x;
  if (gid < KK * KK) w1h[gid] = (_Float16)l1_w[gid];
  else if (gid < KK * KK + HH * KK) w2h[gid - KK * KK] = (_Float16)l2_w[gid - KK * KK];
}

// Grid: 512 blocks = (b, ig); each block handles i = ig*4 + i2, i2 in [0,4).
// 256 threads = 4 waves. Per t, block covers j in [t*64,(t+1)*64); wave w: j = t*64+w*16+lr.
__global__ __launch_bounds__(256, 2) void gbf_main_kernel(
    const float* __restrict__ pos, const float* __restrict__ means,
    const float* __restrict__ stds, const float* __restrict__ mul_w,
    const float* __restrict__ bias_w, const float* __restrict__ l1_b,
    const float* __restrict__ l2_b, const int* __restrict__ x,
    const int* __restrict__ nte, const _Float16* __restrict__ w1h,
    const _Float16* __restrict__ w2h, float* __restrict__ attn_out,
    float* __restrict__ s_out)
{
  // f16 tiles [row][col] with 16B-group XOR swizzle: half_col_group ^= (row&7)
  __shared__ _Float16 w1s[KK * KK];            // 32 KB
  __shared__ _Float16 w2s[HH * KK];            // 8 KB
  __shared__ _Float16 hs[4][16 * KK];          // per-wave h slab, 16 KB
  __shared__ __align__(16) float att[HH][68];  // per-t attn tile, 8.5 KB
  __shared__ float xvs[NN];
  __shared__ float kms[KK], kc2s[KK], kins[KK];
  __shared__ float l1bs[KK], l2bs[HH];
  __shared__ float ssum2[4][KK];
  __shared__ unsigned char vms[NN];

  const int bx = blockIdx.x;
  const int b = bx >> 6, ig = bx & 63;
  const int tid = threadIdx.x;
  const int lane = tid & 63, w = tid >> 6;
  const int g = lane >> 4, lr = lane & 15;

  // ---- per-k constants, valid mask ----
  if (tid < KK) {
    float sd = fabsf(stds[tid]) + 1e-5f;
    float inv = 1.0f / sd;
    kms[tid] = means[tid];
    kc2s[tid] = -0.72134752044448170f * inv * inv;   // -0.5*log2(e)/std^2
    kins[tid] = inv / sqrtf(2.0f * 3.14159f);        // 1/(SQRT_2PI*std)
    l1bs[tid] = l1_b[tid];
    if (tid < HH) l2bs[tid] = l2_b[tid];
  }
  vms[tid] = (x[b * NN + tid] != 0) ? 1 : 0;

  // ---- stage W1, W2 into LDS (f16, swizzled), 16B per thread per iter ----
  for (int idx = tid; idx < (KK * KK) / 8; idx += 256) {   // 8 iters
    const int h = idx >> 4, k8 = idx & 15;
    const f16x8 v = *(const f16x8*)&w1h[idx * 8];
    *(f16x8*)&w1s[(h << 7) + ((k8 ^ (h & 7)) << 3)] = v;
  }
  for (int idx = tid; idx < (HH * KK) / 8; idx += 256) {   // 2 iters
    const int h = idx >> 4, k8 = idx & 15;
    const f16x8 v = *(const f16x8*)&w2h[idx * 8];
    *(f16x8*)&w2s[(h << 7) + ((k8 ^ (h & 7)) << 3)] = v;
  }

  _Float16* hw = &hs[w][0];

  for (int i2 = 0; i2 < 4; ++i2) {
    const int i = ig * 4 + i2;
    const bool valid_i = (x[b * NN + i] != 0);

    // ---- per-j xv for this i ----
    {
      const int j = tid;
      const float pix = pos[(b * NN + i) * 3 + 0];
      const float piy = pos[(b * NN + i) * 3 + 1];
      const float piz = pos[(b * NN + i) * 3 + 2];
      const float dx = pos[(b * NN + j) * 3 + 0] - pix;
      const float dy = pos[(b * NN + j) * 3 + 1] - piy;
      const float dz = pos[(b * NN + j) * 3 + 2] - piz;
      const float sq = dx * dx + dy * dy + dz * dz;
      const float dist = (sq < 1e-4f) ? 100.0f : sqrtf(sq);
      const int base = ((b * NN + i) * NN + j) * 2;
      const int e0 = nte[base], e1 = nte[base + 1];
      const float mul = 0.5f * (mul_w[e0] + mul_w[e1]);
      const float bia = 0.5f * (bias_w[e0] + bias_w[e1]);
      xvs[j] = mul * dist + bia;
    }
    __syncthreads();  // xvs ready (also: W staged on first iter; ssum2 consumed on later iters)

    float sp[32];
#pragma unroll
    for (int z = 0; z < 32; ++z) sp[z] = 0.0f;

    for (int t = 0; t < 4; ++t) {
      const int jg = t * 64 + w * 16 + lr;
      const float xvj = xvs[jg];
      const float efm = (valid_i && vms[jg]) ? 0.0f : 1.0f;

      // ---- gbf into A-fragments (lane: row j = jg, k = ks*32+g*8+ii) ----
      f16x8 afrag[4];
#pragma unroll
      for (int ks = 0; ks < 4; ++ks) {
#pragma unroll
        for (int ii = 0; ii < 8; ++ii) {
          const int k = ks * 32 + g * 8 + ii;
          const float d0 = xvj - kms[k];
          const float e = EXP2(kc2s[k] * d0 * d0) * kins[k];
          sp[ks * 8 + ii] += efm * e;
          afrag[ks][ii] = (_Float16)e;
        }
      }

      // ---- GEMM1: h = gelu(gbf @ W1^T + b1) -> f16 slab ----
#pragma unroll
      for (int ht = 0; ht < 8; ++ht) {
        f32x4 acc = {0.f, 0.f, 0.f, 0.f};
#pragma unroll
        for (int ks = 0; ks < 4; ++ks) {
          const int row = ht * 16 + lr;
          const int kh = (ks * 32 + g * 8) ^ ((row & 7) << 3);
          const f16x8 bf = *(const f16x8*)&w1s[(row << 7) + kh];
          acc = __builtin_amdgcn_mfma_f32_16x16x32_f16(afrag[ks], bf, acc, 0, 0, 0);
        }
        const int hcol = ht * 16 + lr;
        const float bb = l1bs[hcol];
#pragma unroll
        for (int q = 0; q < 4; ++q) {
          const float xh = acc[q] + bb;
          const float gl = 0.5f * xh * (1.0f + erff(xh * 0.70710678118f));
          const int jr = g * 4 + q;
          hw[(jr << 7) + (hcol ^ ((jr & 7) << 3))] = (_Float16)gl;
        }
      }

      // ---- GEMM2 (swapped) -> att tile ----
      const float maskz = (valid_i && vms[jg]) ? 0.0f : 1.0f;
#pragma unroll
      for (int nt2 = 0; nt2 < 2; ++nt2) {
        f32x4 acc = {0.f, 0.f, 0.f, 0.f};
#pragma unroll
        for (int ks = 0; ks < 4; ++ks) {
          const int wrow = nt2 * 16 + lr;
          const f16x8 wf = *(const f16x8*)&w2s[(wrow << 7) + ((ks * 32 + g * 8) ^ ((wrow & 7) << 3))];
          const f16x8 hf = *(const f16x8*)&hw[(lr << 7) + ((ks * 32 + g * 8) ^ ((lr & 7) << 3))];
          acc = __builtin_amdgcn_mfma_f32_16x16x32_f16(wf, hf, acc, 0, 0, 0);
        }
#pragma unroll
        for (int q = 0; q < 4; ++q) {
          const int hout = nt2 * 16 + g * 4 + q;
          att[hout][w * 16 + lr] = (acc[q] + l2bs[hout]) * maskz;
        }
      }
      __syncthreads();

      // ---- flush att tile: 256B contiguous per plane, full lines ----
#pragma unroll
      for (int rp = 0; rp < 2; ++rp) {
        const int plane = rp * 16 + (tid >> 4);
        const int jj = (tid & 15) * 4;
        const f32x4 v = *(const f32x4*)&att[plane][jj];
        *(f32x4*)&attn_out[(b * HH + plane) * (NN * NN) + i * NN + t * 64 + jj] = v;
      }
      __syncthreads();
    }

    // ---- dist_emb partials for this i ----
#pragma unroll
    for (int z = 0; z < 32; ++z) {
      float v = sp[z];
      v += __shfl_xor(v, 1);
      v += __shfl_xor(v, 2);
      v += __shfl_xor(v, 4);
      v += __shfl_xor(v, 8);
      if (lr == 0) ssum2[w][(z >> 3) * 32 + g * 8 + (z & 7)] = v;
    }
    __syncthreads();
    if (tid < KK) {
      s_out[((b * NN + i) << 7) + tid] =
          ssum2[0][tid] + ssum2[1][tid] + ssum2[2][tid] + ssum2[3][tid];
    }
  }
}

// dist_emb = (S @ ep_w^T + ep_b) / 100 ; S is (2048 x 128) fp32
__global__ __launch_bounds__(256) void emb_kernel(
    const float* __restrict__ s_in, const float* __restrict__ ep_w,
    const float* __restrict__ ep_b, float* __restrict__ out)
{
  __shared__ float st[8][KK];
  const int tid = threadIdx.x;
  const int r0 = blockIdx.x * 8;
  for (int idx = tid; idx < 8 * KK; idx += 256)
    st[idx >> 7][idx & 127] = s_in[(r0 << 7) + idx];
  __syncthreads();
#pragma unroll 1
  for (int dd = 0; dd < 3; ++dd) {
    const int d = dd * 256 + tid;
    float acc[8];
#pragma unroll
    for (int r = 0; r < 8; ++r) acc[r] = 0.f;
    const float4* wrow = (const float4*)&ep_w[d << 7];
    for (int k4 = 0; k4 < 32; ++k4) {
      const float4 wv = wrow[k4];
#pragma unroll
      for (int r = 0; r < 8; ++r) {
        acc[r] += st[r][k4 * 4 + 0] * wv.x + st[r][k4 * 4 + 1] * wv.y +
                  st[r][k4 * 4 + 2] * wv.z + st[r][k4 * 4 + 3] * wv.w;
      }
    }
    const float bb = ep_b[d];
#pragma unroll
    for (int r = 0; r < 8; ++r)
      out[(r0 + r) * DD + d] = (acc[r] + bb) * 0.01f;
  }
}

extern "C" void kernel_launch(void* const* d_in, const int* in_sizes, int n_in,
                              void* d_out, int out_size, void* d_ws, size_t ws_size,
                              hipStream_t stream) {
  const float* pos    = (const float*)d_in[0];
  const float* means  = (const float*)d_in[1];
  const float* stds   = (const float*)d_in[2];
  const float* mul_w  = (const float*)d_in[3];
  const float* bias_w = (const float*)d_in[4];
  const float* l1_w   = (const float*)d_in[5];
  const float* l1_b   = (const float*)d_in[6];
  const float* l2_w   = (const float*)d_in[7];
  const float* l2_b   = (const float*)d_in[8];
  const float* ep_w   = (const float*)d_in[9];
  const float* ep_b   = (const float*)d_in[10];
  const int*   x      = (const int*)d_in[11];
  const int*   nte    = (const int*)d_in[12];

  float* out      = (float*)d_out;
  float* dist_emb = out;                 // (8,256,768)
  float* attn     = out + NB * NN * DD;  // (8,32,256,256)

  _Float16* w1h = (_Float16*)d_ws;                        // 32 KB
  _Float16* w2h = (_Float16*)((char*)d_ws + 32768);       // 8 KB
  float*    s_ws = (float*)((char*)d_ws + 49152);         // 1 MB

  hipLaunchKernelGGL(prep_kernel, dim3(80), dim3(256), 0, stream,
                     l1_w, l2_w, w1h, w2h);
  hipLaunchKernelGGL(gbf_main_kernel, dim3(512), dim3(256), 0, stream,
                     pos, means, stds, mul_w, bias_w, l1_b, l2_b,
                     x, nte, w1h, w2h, attn, s_ws);
  hipLaunchKernelGGL(emb_kernel, dim3(NB * NN / 8), dim3(256), 0, stream,
                     s_ws, ep_w, ep_b, dist_emb);
}